// Round 3
// baseline (283.197 us; speedup 1.0000x reference)
//
#include <hip/hip_runtime.h>
#include <math.h>

#define N 8192
#define N_MODES 12
#define GRID 2048
#define BLK 256
// float4 slots per row = N/4 = 2048
// grid stride = GRID*BLK = 524,288 slots = exactly 256 rows -> per-thread
// column c is loop-invariant; row advances by 256 each iteration.

// H[i][j] = 0 except:
//   H[i][i]   = 2*inv_dx2 + V[i]
//   H[i][i±1] = -inv_dx2
// V[i] = a0 + sum_k cos_c[k]*cos(2*pi*(k+1)*x_i) + sin_c[k]*sin(2*pi*(k+1)*x_i)
// x_i = i / (N-1)
//
// Findings baked in:
//  - The ~160us 1.074GB fills in the profile are the HARNESS's poison of the
//    output allocation (persist with no memset in our code). Untouchable floor.
//  - Plain cached float4 stores ran at ~2.5 TB/s (L2/L3 write-allocate +
//    dirty-line evictions vs the poison fill). Vendor fill hits 6.6 TB/s.
//  - Fix: nontemporal stores. NOTE: __builtin_nontemporal_store requires a
//    native clang vector type, not HIP's struct float4 (R2 compile error).

typedef float floatx4 __attribute__((ext_vector_type(4)));

__global__ __launch_bounds__(BLK) void schro_fused_fill_nt(
    const float* __restrict__ a0,
    const float* __restrict__ cos_c,
    const float* __restrict__ sin_c,
    float* __restrict__ out)
{
    const float inv_dx2 = 67108864.0f;  // 8192^2

    const int q0  = blockIdx.x * BLK + threadIdx.x;   // first float4 slot
    const int c   = (q0 << 2) & (N - 1);              // col of slot (invariant)
    int row       = q0 >> 11;                         // q0 / 2048

    floatx4* __restrict__ p = (floatx4*)out + q0;

    #pragma unroll 1
    for (int it = 0; it < 32; ++it) {
        floatx4 v = (floatx4)(0.0f);

        // Band cols {row-1, row, row+1} vs this slot's cols [c, c+3]:
        // intersect iff row - c in [-1, 4].
        if ((unsigned)(row - c + 1) <= 5u) {
            // V[row] -- identical math to the absmax=0.0 kernels.
            const float x = (float)row * (1.0f / (float)(N - 1));
            float V = a0[0];
            #pragma unroll
            for (int k = 0; k < N_MODES; ++k) {
                const float ph = 6.28318530717958647692f * (float)(k + 1) * x;
                V += cos_c[k] * cosf(ph) + sin_c[k] * sinf(ph);
            }
            const float diagv = 2.0f * inv_dx2 + V;

            #pragma unroll
            for (int j = 0; j < 4; ++j) {
                const int col = c + j;
                if (col == row)                            v[j] = diagv;
                else if (col == row - 1 || col == row + 1) v[j] = -inv_dx2;
            }
        }

        __builtin_nontemporal_store(v, p);  // bypass L2/L3 dirty-evict path
        p   += GRID * BLK;
        row += 256;
    }
}

extern "C" void kernel_launch(void* const* d_in, const int* in_sizes, int n_in,
                              void* d_out, int out_size, void* d_ws, size_t ws_size,
                              hipStream_t stream) {
    const float* a0    = (const float*)d_in[0];
    const float* cos_c = (const float*)d_in[1];
    const float* sin_c = (const float*)d_in[2];
    float* out = (float*)d_out;

    schro_fused_fill_nt<<<GRID, BLK, 0, stream>>>(a0, cos_c, sin_c, out);
}

// Round 4
// 255.369 us; speedup vs baseline: 1.1090x; 1.1090x over previous
//
#include <hip/hip_runtime.h>
#include <math.h>

#define N 8192
#define N_MODES 12
#define BLK 256
#define ROWS_PER_BLOCK 4
#define GRID (N / ROWS_PER_BLOCK)   // 2048 blocks, 8 per CU

// H[i][j] = 0 except:
//   H[i][i]   = 2*inv_dx2 + V[i]
//   H[i][i±1] = -inv_dx2
// V[i] = a0 + sum_k cos_c[k]*cos(2*pi*(k+1)*x_i) + sin_c[k]*sin(2*pi*(k+1)*x_i)
// x_i = i / (N-1)
//
// Timing model (R0-R3 evidence): every timed iteration = harness poison fill
// (1.074 GB, ~162 us, untouchable) + our work. Fused grid-stride kernel ran
// at only ~2.5 TB/s vs vendor fill's 6.6; NT stores changed nothing (R3), so
// not a cache effect. R4 attacks the two remaining suspects:
//  1) TLB/page locality: grid-stride jumped 8 MB per iteration per thread.
//     Now each block owns 4 CONTIGUOUS rows (128 KB) and walks them linearly,
//     exactly like the vendor fill.
//  2) trig register pressure on every wave: V is now computed ONCE per block
//     by 4 threads into LDS; the hot loop is a branch-free unrolled dwordx4
//     zero stream. Band entries are patched after a __syncthreads() (hipcc
//     drains vmcnt(0) before s_barrier, so fill stores are ordered first).

typedef float floatx4 __attribute__((ext_vector_type(4)));

__global__ __launch_bounds__(BLK) void schro_fill_band(
    const float* __restrict__ a0,
    const float* __restrict__ cos_c,
    const float* __restrict__ sin_c,
    float* __restrict__ out)
{
    const float inv_dx2 = 67108864.0f;  // 8192^2
    __shared__ float Vsh[ROWS_PER_BLOCK];

    const int b = blockIdx.x;
    const int t = threadIdx.x;

    // --- 1. V for this block's 4 rows (identical math to the absmax=0 kernels)
    if (t < ROWS_PER_BLOCK) {
        const int row = b * ROWS_PER_BLOCK + t;
        const float x = (float)row * (1.0f / (float)(N - 1));
        float V = a0[0];
        #pragma unroll
        for (int k = 0; k < N_MODES; ++k) {
            const float ph = 6.28318530717958647692f * (float)(k + 1) * x;
            V += cos_c[k] * cosf(ph) + sin_c[k] * sinf(ph);
        }
        Vsh[t] = V;
    }

    // --- 2. stream zeros over the block's 128 KB contiguous region
    // slots per block = 4 rows * (N/4) float4 = 8192; 32 per thread.
    floatx4* __restrict__ p =
        (floatx4*)out + (size_t)b * (ROWS_PER_BLOCK * (N / 4)) + t;
    const floatx4 z = (floatx4)(0.0f);
    #pragma unroll
    for (int it = 0; it < 32; ++it) {
        p[(size_t)it * BLK] = z;   // wave: 1 KB contiguous; block walks 128 KB
    }

    __syncthreads();  // vmcnt(0) drain + barrier: zeros committed before patch

    // --- 3. patch the tridiagonal band (rows owned exclusively by this block)
    if (t < ROWS_PER_BLOCK) {
        const int row = b * ROWS_PER_BLOCK + t;
        float* o = out + (size_t)row * N;
        o[row] = 2.0f * inv_dx2 + Vsh[t];
        if (row > 0)     o[row - 1] = -inv_dx2;
        if (row < N - 1) o[row + 1] = -inv_dx2;
    }
}

extern "C" void kernel_launch(void* const* d_in, const int* in_sizes, int n_in,
                              void* d_out, int out_size, void* d_ws, size_t ws_size,
                              hipStream_t stream) {
    const float* a0    = (const float*)d_in[0];
    const float* cos_c = (const float*)d_in[1];
    const float* sin_c = (const float*)d_in[2];
    float* out = (float*)d_out;

    schro_fill_band<<<GRID, BLK, 0, stream>>>(a0, cos_c, sin_c, out);
}

// Round 5
// 254.326 us; speedup vs baseline: 1.1135x; 1.0041x over previous
//
#include <hip/hip_runtime.h>
#include <math.h>

#define N 8192
#define N_MODES 12

// H[i][j] = 0 except:
//   H[i][i]   = 2*inv_dx2 + V[i]
//   H[i][i±1] = -inv_dx2
// V[i] = a0 + sum_k cos_c[k]*cos(2*pi*(k+1)*x_i) + sin_c[k]*sin(2*pi*(k+1)*x_i)
// x_i = i / (N-1)   (linspace(0,1,N) endpoint-inclusive)
//
// Session model (R0-R4 evidence):
//  - Every timed iteration carries an untouchable harness poison fill of the
//    output allocation: 1.074 GB @ ~162 us (top-5 fills persist with no
//    memset of ours in flight).
//  - out_size is an ELEMENT count: R0's memset(out, 0, out_size*4) wrote
//    exactly 268 MB at vendor rate (~41 us) -- if it had been 1.074 GB the
//    R0 total would exceed 324 us.
//  - Best fused single-kernel fill (R4, page-local) ties memset+band at
//    93 us of stream time; NT stores (R3) and grid-stride (R1) were worse.
//    The vendor fill path is the fastest known way to put down the zeros.
//  - Remaining ambiguity: R0's band kernel ran on only 32 blocks (32/256
//    CUs). This round widens it to 128 blocks x 64 threads (1 row/thread,
//    one wave per CU across half the chip) to close the latency-hiding gap.
//    If total doesn't move, the residual is fixed harness overhead and we
//    are at the floor: 162 (poison) + 41 (min 268 MB write) + fixed.

__global__ __launch_bounds__(64) void schro_band_kernel(
    const float* __restrict__ a0,
    const float* __restrict__ cos_c,
    const float* __restrict__ sin_c,
    float* __restrict__ out)
{
    const int row = blockIdx.x * 64 + threadIdx.x;   // grid covers all 8192 rows
    const float inv_dx2 = 67108864.0f;               // 8192^2

    // V[row] -- identical math to every absmax=0.0 kernel this session.
    const float x = (float)row * (1.0f / (float)(N - 1));
    float V = a0[0];
    #pragma unroll
    for (int k = 0; k < N_MODES; ++k) {
        const float ph = 6.28318530717958647692f * (float)(k + 1) * x;
        V += cos_c[k] * cosf(ph) + sin_c[k] * sinf(ph);
    }

    float* o = out + (size_t)row * N;
    o[row] = 2.0f * inv_dx2 + V;
    if (row > 0)     o[row - 1] = -inv_dx2;
    if (row < N - 1) o[row + 1] = -inv_dx2;
}

extern "C" void kernel_launch(void* const* d_in, const int* in_sizes, int n_in,
                              void* d_out, int out_size, void* d_ws, size_t ws_size,
                              hipStream_t stream) {
    const float* a0    = (const float*)d_in[0];
    const float* cos_c = (const float*)d_in[1];
    const float* sin_c = (const float*)d_in[2];
    float* out = (float*)d_out;

    // Zero the 268 MB matrix on the vendor fill path (~6.6 TB/s measured on
    // this very buffer). out_size is an element count (see header comment).
    hipMemsetAsync(out, 0, (size_t)out_size * sizeof(float), stream);

    // Band writes: 1 row/thread, 128 blocks x 64 threads = one wave on each
    // of 128 CUs (R0 used 32 blocks -> 32 CUs, latency-unhidden).
    schro_band_kernel<<<N / 64, 64, 0, stream>>>(a0, cos_c, sin_c, out);
}